// Round 3
// baseline (274.787 us; speedup 1.0000x reference)
//
#include <hip/hip_runtime.h>
#include <math.h>

#define V_ 32000
#define E_ 512
#define H_ 1024
#define N_ 64
#define S_ 2048

typedef short bf16x8 __attribute__((ext_vector_type(8)));
typedef float f32x4 __attribute__((ext_vector_type(4)));

__device__ __forceinline__ float sigmoidf_(float x) { return 1.0f / (1.0f + expf(-x)); }

__device__ __forceinline__ unsigned f2bf_u(float f) {  // RNE f32->bf16 bits
  unsigned a = __float_as_uint(f);
  return (a + 0x7fffu + ((a >> 16) & 1u)) >> 16;
}
__device__ __forceinline__ unsigned pk2(float lo, float hi) {
  return f2bf_u(lo) | (f2bf_u(hi) << 16);
}
__device__ __forceinline__ unsigned short f2bf(float f) { return (unsigned short)f2bf_u(f); }

// ---------------------------------------------------------------------------
// Build Zt1 [1536][64]
// ---------------------------------------------------------------------------
__global__ __launch_bounds__(256) void k_build_zt1(
    const int* __restrict__ prev_out, const float* __restrict__ h0,
    const float* __restrict__ embW, float* __restrict__ Zt1) {
  int idx = blockIdx.x * 256 + threadIdx.x;
  int n = idx & 63, k = idx >> 6;
  float v;
  if (k < E_) v = embW[(size_t)prev_out[n] * E_ + k];
  else        v = h0[n * H_ + (k - E_)];
  Zt1[idx] = v;
}

// ---------------------------------------------------------------------------
// f32 gates GEMM, K-split x4. Stores TRANSPOSED: Cpart[part][n(64)][j(4096)]
// so the LSTM kernel reads coalesced.
// ---------------------------------------------------------------------------
__global__ __launch_bounds__(256) void k_gemm64t(
    const float* __restrict__ W1, int S1, int K1,
    const float* __restrict__ W2, int S2,
    const float* __restrict__ Zt, float* __restrict__ Cpart, int klen) {
  const int t = threadIdx.x;
  const int j0 = blockIdx.x * 64;
  const int part = blockIdx.y;
  const int kbeg = part * klen;
  const int kend = kbeg + klen;

  __shared__ float zt[32][64];
  __shared__ float wt[32][68];

  const int tc = t & 15;
  const int tr = t >> 4;
  const int jw = t >> 2;
  const int kq = (t & 3) * 8;

  float acc[4][4];
#pragma unroll
  for (int i = 0; i < 4; i++)
#pragma unroll
    for (int j = 0; j < 4; j++) acc[i][j] = 0.f;

  for (int k0 = kbeg; k0 < kend; k0 += 32) {
    const float4* zsrc = (const float4*)(Zt + (size_t)k0 * 64);
    float4 z0 = zsrc[t * 2];
    float4 z1 = zsrc[t * 2 + 1];
    const float* Wp; int stride, kb;
    if (k0 < K1) { Wp = W1; stride = S1; kb = k0; }
    else         { Wp = W2; stride = S2; kb = k0 - K1; }
    const float* wrow = Wp + (size_t)(j0 + jw) * stride + kb + kq;
    float4 wa = *(const float4*)(wrow);
    float4 wb = *(const float4*)(wrow + 4);

    __syncthreads();
    ((float4*)(&zt[0][0]))[t * 2]     = z0;
    ((float4*)(&zt[0][0]))[t * 2 + 1] = z1;
    wt[kq + 0][jw] = wa.x; wt[kq + 1][jw] = wa.y;
    wt[kq + 2][jw] = wa.z; wt[kq + 3][jw] = wa.w;
    wt[kq + 4][jw] = wb.x; wt[kq + 5][jw] = wb.y;
    wt[kq + 6][jw] = wb.z; wt[kq + 7][jw] = wb.w;
    __syncthreads();

#pragma unroll 8
    for (int k = 0; k < 32; k++) {
      float4 z = *(const float4*)(&zt[k][tc * 4]);
      float4 w = *(const float4*)(&wt[k][tr * 4]);
      acc[0][0] += w.x * z.x; acc[0][1] += w.x * z.y; acc[0][2] += w.x * z.z; acc[0][3] += w.x * z.w;
      acc[1][0] += w.y * z.x; acc[1][1] += w.y * z.y; acc[1][2] += w.y * z.z; acc[1][3] += w.y * z.w;
      acc[2][0] += w.z * z.x; acc[2][1] += w.z * z.y; acc[2][2] += w.z * z.z; acc[2][3] += w.z * z.w;
      acc[3][0] += w.w * z.x; acc[3][1] += w.w * z.y; acc[3][2] += w.w * z.z; acc[3][3] += w.w * z.w;
    }
  }

  float* cp = Cpart + (size_t)part * 4096 * 64;  // [n][j]
#pragma unroll
  for (int nn = 0; nn < 4; nn++) {
    int n = tc * 4 + nn;
    float4 o = make_float4(acc[0][nn], acc[1][nn], acc[2][nn], acc[3][nn]);
    *(float4*)(cp + (size_t)n * 4096 + j0 + tr * 4) = o;
  }
}

// ---------------------------------------------------------------------------
// LSTM cell + K-split reduce (coalesced gpart reads via transposed layout)
// ---------------------------------------------------------------------------
__global__ __launch_bounds__(256) void k_lstm_fused(
    const float* __restrict__ gpart, const float* __restrict__ b_ih,
    const float* __restrict__ b_hh, const float* __restrict__ c0,
    float* __restrict__ out_h, float* __restrict__ out_c,
    unsigned short* __restrict__ concat_bf) {
  int idx = blockIdx.x * 256 + threadIdx.x;  // 64*1024
  int n = idx >> 10, hh = idx & 1023;
  float g[4];
#pragma unroll
  for (int ga = 0; ga < 4; ga++) {
    float s = b_ih[ga * H_ + hh] + b_hh[ga * H_ + hh];
#pragma unroll
    for (int p = 0; p < 4; p++)
      s += gpart[((size_t)p * 64 + n) * 4096 + ga * H_ + hh];
    g[ga] = s;
  }
  float cv = sigmoidf_(g[1]) * c0[idx] + sigmoidf_(g[0]) * tanhf(g[2]);
  float hv = sigmoidf_(g[3]) * tanhf(cv);
  out_h[idx] = hv;
  out_c[idx] = cv;
  concat_bf[(size_t)n * 2048 + hh] = f2bf(hv);
}

// ---------------------------------------------------------------------------
// fc half-GEMM device body: out[n][v0+..] (+)= W[v][0..1024) @ B[n][0..1024)
//   W row stride 2048 f32 (caller offsets base by k-offset)
//   Bmat row stride 2048 bf16 (caller offsets)
//   bias != nullptr: out = acc + bias;  bias == nullptr: out += acc (RMW)
// A frags: direct global->reg->bf16 (no LDS). B: LDS staged, T2 swizzle.
// k-chunk = 128 (4 MFMA k-steps), one-chunk register prefetch.
// ---------------------------------------------------------------------------
__device__ __forceinline__ void fc_half(
    const float* __restrict__ W, const unsigned short* __restrict__ Bmat,
    const float* __restrict__ bias, float* __restrict__ outNV,
    int v0, int t, unsigned char* smem) {
  const int w = t >> 6, lane = t & 63;
  const int arow = v0 + (w << 4) + (lane & 15);
  const int koct = lane >> 4;  // 0..3
  const float* aptr = W + (size_t)arow * 2048 + koct * 8;

  // B staging: thread -> row bn=t>>2, quarter bq=t&3 (32 k each, 4x16B slots)
  const int bn = t >> 2, bq = t & 3;
  const unsigned short* bptr = Bmat + (size_t)bn * 2048 + bq * 32;
  unsigned bwo[4];
#pragma unroll
  for (int j = 0; j < 4; j++)
    bwo[j] = bn * 256 + (((bq * 4 + j) * 16) ^ ((bn & 7) << 4));

  f32x4 acc[4] = {{0.f,0.f,0.f,0.f},{0.f,0.f,0.f,0.f},{0.f,0.f,0.f,0.f},{0.f,0.f,0.f,0.f}};

  float4 pa[8];
  uint4 pb[4];
#pragma unroll
  for (int s = 0; s < 4; s++) {
    pa[2*s]   = *(const float4*)(aptr + s * 32);
    pa[2*s+1] = *(const float4*)(aptr + s * 32 + 4);
  }
#pragma unroll
  for (int j = 0; j < 4; j++) pb[j] = *(const uint4*)(bptr + j * 8);

  for (int c = 0; c < 8; c++) {
    __syncthreads();  // prior chunk's B reads complete
#pragma unroll
    for (int j = 0; j < 4; j++) *(uint4*)(smem + bwo[j]) = pb[j];
    // pack A for this chunk
    bf16x8 af[4];
#pragma unroll
    for (int s = 0; s < 4; s++) {
      uint4 p;
      p.x = pk2(pa[2*s].x,   pa[2*s].y);   p.y = pk2(pa[2*s].z,   pa[2*s].w);
      p.z = pk2(pa[2*s+1].x, pa[2*s+1].y); p.w = pk2(pa[2*s+1].z, pa[2*s+1].w);
      af[s] = *(bf16x8*)&p;
    }
    // prefetch next chunk (covers HBM latency under this chunk's MFMA)
    if (c < 7) {
      const float* ap = aptr + (c + 1) * 128;
#pragma unroll
      for (int s = 0; s < 4; s++) {
        pa[2*s]   = *(const float4*)(ap + s * 32);
        pa[2*s+1] = *(const float4*)(ap + s * 32 + 4);
      }
      const unsigned short* bp = bptr + (c + 1) * 128;
#pragma unroll
      for (int j = 0; j < 4; j++) pb[j] = *(const uint4*)(bp + j * 8);
    }
    __syncthreads();  // B chunk visible
#pragma unroll
    for (int s = 0; s < 4; s++) {
#pragma unroll
      for (int nf = 0; nf < 4; nf++) {
        int br = nf * 16 + (lane & 15);
        bf16x8 bfrag = *(const bf16x8*)(smem + br * 256 +
                         (((s * 4 + koct) * 16) ^ ((br & 7) << 4)));
        acc[nf] = __builtin_amdgcn_mfma_f32_16x16x32_bf16(af[s], bfrag, acc[nf], 0, 0, 0);
      }
    }
  }

  // D: col = lane&15 (n), row = (lane>>4)*4 + reg (v within 16)
  const int vrow = v0 + (w << 4) + ((lane >> 4) << 2);
#pragma unroll
  for (int nf = 0; nf < 4; nf++) {
    int n = nf * 16 + (lane & 15);
    float* op = outNV + (size_t)n * V_ + vrow;
    float4 o;
    if (bias) {
      float4 b4 = *(const float4*)(bias + vrow);
      o = make_float4(acc[nf][0] + b4.x, acc[nf][1] + b4.y,
                      acc[nf][2] + b4.z, acc[nf][3] + b4.w);
    } else {
      float4 prev = *(const float4*)op;
      o = make_float4(prev.x + acc[nf][0], prev.y + acc[nf][1],
                      prev.z + acc[nf][2], prev.w + acc[nf][3]);
    }
    *(float4*)op = o;
  }
}

// ---------------------------------------------------------------------------
// attn device body (single enc pass); smem: hs at [0,4KB), cbuf at [4KB,20KB)
// ---------------------------------------------------------------------------
__device__ __forceinline__ void attn_body(
    const float* __restrict__ enc, const float* __restrict__ h,
    float* __restrict__ ctxPart, int c, int n, int t, unsigned char* smem) {
  const int w = t >> 6, lane = t & 63;
  float* hs = (float*)smem;                 // 4 KB
  float* cbuf = (float*)(smem + 4096);      // 16 KB: [4][1024]

  ((float4*)hs)[t] = ((const float4*)(h + (size_t)n * H_))[t];
  __syncthreads();

  const float4* hp = (const float4*)hs;
  float4 hv0 = hp[lane], hv1 = hp[64 + lane], hv2 = hp[128 + lane], hv3 = hp[192 + lane];

  float ca[16];
#pragma unroll
  for (int i = 0; i < 16; i++) ca[i] = 0.f;

  for (int si = w; si < 128; si += 4) {
    const int s = c * 128 + si;
    const float4* row = (const float4*)(enc + ((size_t)n * S_ + s) * H_);
    float4 e0 = row[lane], e1 = row[64 + lane], e2 = row[128 + lane], e3 = row[192 + lane];
    float d = e0.x * hv0.x + e0.y * hv0.y + e0.z * hv0.z + e0.w * hv0.w
            + e1.x * hv1.x + e1.y * hv1.y + e1.z * hv1.z + e1.w * hv1.w
            + e2.x * hv2.x + e2.y * hv2.y + e2.z * hv2.z + e2.w * hv2.w
            + e3.x * hv3.x + e3.y * hv3.y + e3.z * hv3.z + e3.w * hv3.w;
#pragma unroll
    for (int m = 32; m; m >>= 1) d += __shfl_xor(d, m, 64);
    ca[0]  += d * e0.x; ca[1]  += d * e0.y; ca[2]  += d * e0.z; ca[3]  += d * e0.w;
    ca[4]  += d * e1.x; ca[5]  += d * e1.y; ca[6]  += d * e1.z; ca[7]  += d * e1.w;
    ca[8]  += d * e2.x; ca[9]  += d * e2.y; ca[10] += d * e2.z; ca[11] += d * e2.w;
    ca[12] += d * e3.x; ca[13] += d * e3.y; ca[14] += d * e3.z; ca[15] += d * e3.w;
  }

  float4* cb = (float4*)(cbuf + w * H_);
  cb[0 * 64 + lane] = make_float4(ca[0], ca[1], ca[2], ca[3]);
  cb[1 * 64 + lane] = make_float4(ca[4], ca[5], ca[6], ca[7]);
  cb[2 * 64 + lane] = make_float4(ca[8], ca[9], ca[10], ca[11]);
  cb[3 * 64 + lane] = make_float4(ca[12], ca[13], ca[14], ca[15]);
  __syncthreads();

  float4 a0 = ((const float4*)(cbuf + 0 * H_))[t];
  float4 a1 = ((const float4*)(cbuf + 1 * H_))[t];
  float4 a2 = ((const float4*)(cbuf + 2 * H_))[t];
  float4 a3 = ((const float4*)(cbuf + 3 * H_))[t];
  float4 r = make_float4(a0.x + a1.x + a2.x + a3.x, a0.y + a1.y + a2.y + a3.y,
                         a0.z + a1.z + a2.z + a3.z, a0.w + a1.w + a2.w + a3.w);
  ((float4*)ctxPart)[((size_t)(n * 16 + c)) * 256 + t] = r;
}

// ---------------------------------------------------------------------------
// MEGA: 1524 blocks. Striped roles: bid%3==2 (bid<1500) -> fc_h tile, else attn.
// fc_h: logits[n][v] = fc_W[v][0:1024) @ h_bf + fc_b  (the h-dependent half)
// ---------------------------------------------------------------------------
__global__ __launch_bounds__(256) void k_mega(
    const float* __restrict__ enc, const float* __restrict__ h,
    float* __restrict__ ctxPart,
    const float* __restrict__ fcW, const unsigned short* __restrict__ concat_bf,
    const float* __restrict__ fc_b, float* __restrict__ logits) {
  __shared__ __align__(16) unsigned char smem[20480];
  const int bid = blockIdx.x;
  const int t = threadIdx.x;
  if (bid < 1500 && (bid % 3) == 2) {
    int v0 = (bid / 3) * 64;
    fc_half(fcW, concat_bf, fc_b, logits, v0, t, smem);
  } else {
    int attn_id = (bid < 1500) ? ((bid / 3) * 2 + (bid % 3)) : (1000 + (bid - 1500));
    attn_body(enc, h, ctxPart, attn_id & 15, attn_id >> 4, t, smem);
  }
}

// ---------------------------------------------------------------------------
// fc ctx half (serial after attn): logits += fc_W[v][1024:2048) @ ctx_bf
// ---------------------------------------------------------------------------
__global__ __launch_bounds__(256) void k_fc2(
    const float* __restrict__ fcW, const unsigned short* __restrict__ concat_bf,
    float* __restrict__ logits) {
  __shared__ __align__(16) unsigned char smem[16384];
  fc_half(fcW + 1024, concat_bf + 1024, nullptr, logits,
          blockIdx.x * 64, threadIdx.x, smem);
}

// ---------------------------------------------------------------------------
// Reduce 16 context partials -> concat ctx half (bf16)
// ---------------------------------------------------------------------------
__global__ __launch_bounds__(256) void k_ctxreduce_bf(
    const float* __restrict__ ctxPart, unsigned short* __restrict__ concat_bf) {
  int idx = blockIdx.x * 256 + threadIdx.x;  // 64*1024
  int n = idx >> 10, hh = idx & 1023;
  float s = 0.f;
  for (int c = 0; c < 16; c++) s += ctxPart[((size_t)(n * 16 + c)) * H_ + hh];
  concat_bf[(size_t)n * 2048 + H_ + hh] = f2bf(s);
}

// ---------------------------------------------------------------------------
// softmax stats, 1024 threads per row
// ---------------------------------------------------------------------------
__global__ __launch_bounds__(1024) void k_smstats_rm(
    const float* __restrict__ logits, float* __restrict__ stats) {
  const int n = blockIdx.x, t = threadIdx.x;
  const float* row = logits + (size_t)n * V_;
  float m = -INFINITY, s = 0.f;
  for (int v = t; v < V_; v += 1024) {
    float x = row[v];
    if (x > m) { s = s * expf(m - x) + 1.f; m = x; }
    else       { s += expf(x - m); }
  }
  __shared__ float ms[1024], ss[1024];
  ms[t] = m; ss[t] = s;
  __syncthreads();
  for (int off = 512; off; off >>= 1) {
    if (t < off) {
      float m2 = ms[t + off], s2 = ss[t + off];
      float M = fmaxf(ms[t], m2);
      ss[t] = ss[t] * expf(ms[t] - M) + s2 * expf(m2 - M);
      ms[t] = M;
    }
    __syncthreads();
  }
  if (t == 0) { stats[n * 2] = ms[0]; stats[n * 2 + 1] = logf(ss[0]); }
}

// ---------------------------------------------------------------------------
// In-place logp, float4
// ---------------------------------------------------------------------------
__global__ __launch_bounds__(256) void k_logp_rm(
    float* __restrict__ logits, const float* __restrict__ stats) {
  const int v4 = blockIdx.x * 256 + threadIdx.x;  // float4 index, 8000 per row
  if (v4 >= V_ / 4) return;
  const int n = blockIdx.y;
  float sub = stats[n * 2] + stats[n * 2 + 1];
  float4* p = (float4*)(logits + (size_t)n * V_) + v4;
  float4 x = *p;
  *p = make_float4(x.x - sub, x.y - sub, x.z - sub, x.w - sub);
}

// ---------------------------------------------------------------------------
extern "C" void kernel_launch(void* const* d_in, const int* in_sizes, int n_in,
                              void* d_out, int out_size, void* d_ws, size_t ws_size,
                              hipStream_t stream) {
  const int*   prev_out = (const int*)d_in[0];
  const float* h0   = (const float*)d_in[1];
  const float* c0   = (const float*)d_in[2];
  const float* enc  = (const float*)d_in[3];
  const float* embW = (const float*)d_in[4];
  const float* w_ih = (const float*)d_in[5];
  const float* w_hh = (const float*)d_in[6];
  const float* b_ih = (const float*)d_in[7];
  const float* b_hh = (const float*)d_in[8];
  const float* fc_W = (const float*)d_in[9];
  const float* fc_b = (const float*)d_in[10];

  float* out = (float*)d_out;
  float* logp  = out;                       // N*V (logits -> logp in place)
  float* out_h = out + (size_t)N_ * V_;     // N*H
  float* out_c = out_h + (size_t)N_ * H_;   // N*H

  char* wsb = (char*)d_ws;
  float* Zt1     = (float*)wsb; wsb += (size_t)1536 * 64 * 4;          // 384 KB
  float* gpart   = (float*)wsb; wsb += (size_t)4 * 4096 * 64 * 4;      // 4 MB
  float* ctxPart = (float*)wsb; wsb += (size_t)16 * 64 * H_ * 4;       // 4 MB
  unsigned short* concat_bf = (unsigned short*)wsb; wsb += (size_t)64 * 2048 * 2;
  float* stats   = (float*)wsb; wsb += 64 * 2 * 4;

  // 1. Z for gates GEMM
  k_build_zt1<<<384, 256, 0, stream>>>(prev_out, h0, embW, Zt1);
  // 2. gates (K-split x4, transposed store)
  k_gemm64t<<<dim3(4096 / 64, 4), 256, 0, stream>>>(
      w_ih, E_, E_, w_hh, H_, Zt1, gpart, 384);
  // 3. LSTM -> h,c (d_out), h -> concat_bf[.., 0:1024)
  k_lstm_fused<<<64 * H_ / 256, 256, 0, stream>>>(gpart, b_ih, b_hh, c0,
                                                  out_h, out_c, concat_bf);
  // 4. MEGA: attention (enc pass) OVERLAPPED with fc h-half (W stream)
  k_mega<<<1524, 256, 0, stream>>>(enc, out_h, ctxPart, fc_W, concat_bf,
                                   fc_b, logp);
  // 5. ctx reduce -> concat_bf[.., 1024:2048)
  k_ctxreduce_bf<<<64 * H_ / 256, 256, 0, stream>>>(ctxPart, concat_bf);
  // 6. fc ctx-half accumulate
  k_fc2<<<V_ / 64, 256, 0, stream>>>(fc_W, concat_bf, logp);
  // 7. log_softmax in place
  k_smstats_rm<<<64, 1024, 0, stream>>>(logp, stats);
  k_logp_rm<<<dim3((V_ / 4 + 255) / 256, N_), 256, 0, stream>>>(logp, stats);
}